// Round 4
// baseline (500.298 us; speedup 1.0000x reference)
//
#include <hip/hip_runtime.h>
#include <hip/hip_bf16.h>

#define D 128

// ---------------- CSR build ----------------

__global__ void k_count(const int* __restrict__ dst, int E, int* __restrict__ cnt) {
    int e = blockIdx.x * blockDim.x + threadIdx.x;
    if (e < E) atomicAdd(&cnt[dst[e]], 1);
}

// per-block sums of cnt
__global__ __launch_bounds__(256) void k_scan1(const int* __restrict__ cnt, int n,
                                               int* __restrict__ bsum) {
    int i = blockIdx.x * 256 + threadIdx.x;
    int x = (i < n) ? cnt[i] : 0;
    #pragma unroll
    for (int off = 32; off > 0; off >>= 1) x += __shfl_xor(x, off, 64);
    __shared__ int ws[4];
    if ((threadIdx.x & 63) == 0) ws[threadIdx.x >> 6] = x;
    __syncthreads();
    if (threadIdx.x == 0) bsum[blockIdx.x] = ws[0] + ws[1] + ws[2] + ws[3];
}

// exclusive scan of block sums (nb <= 256), single block of 256
__global__ void k_scan2(const int* __restrict__ bsum, int nb, int* __restrict__ boff) {
    int t = threadIdx.x;
    int lane = t & 63, wid = t >> 6;
    int x = (t < nb) ? bsum[t] : 0;
    int incl = x;
    #pragma unroll
    for (int off = 1; off < 64; off <<= 1) {
        int y = __shfl_up(incl, off, 64);
        if (lane >= off) incl += y;
    }
    __shared__ int ws[4];
    if (lane == 63) ws[wid] = incl;
    __syncthreads();
    int o = 0;
    for (int w = 0; w < wid; w++) o += ws[w];
    if (t < nb) boff[t] = o + incl - x;
}

// final: row_ptr/cursor/dinv
__global__ __launch_bounds__(256) void k_scan3(const int* __restrict__ cnt,
                                               const int* __restrict__ boff, int n, int E,
                                               int* __restrict__ row_ptr, int* __restrict__ cursor,
                                               float* __restrict__ dinv) {
    int t = threadIdx.x;
    int lane = t & 63, wid = t >> 6;
    int i = blockIdx.x * 256 + t;
    int x = (i < n) ? cnt[i] : 0;
    int incl = x;
    #pragma unroll
    for (int off = 1; off < 64; off <<= 1) {
        int y = __shfl_up(incl, off, 64);
        if (lane >= off) incl += y;
    }
    __shared__ int ws[4];
    if (lane == 63) ws[wid] = incl;
    __syncthreads();
    int o = boff[blockIdx.x];
    for (int w = 0; w < wid; w++) o += ws[w];
    if (i < n) {
        int excl = o + incl - x;
        row_ptr[i] = excl;
        cursor[i] = excl;
        dinv[i] = rsqrtf((float)(x + 1));  // +1 self loop
    }
    if (blockIdx.x == 0 && t == 0) row_ptr[n] = E;
}

__global__ void k_fill(const int* __restrict__ src, const int* __restrict__ dst, int E,
                       int* __restrict__ cursor, int* __restrict__ esrc) {
    int e = blockIdx.x * blockDim.x + threadIdx.x;
    if (e < E) {
        int p = atomicAdd(&cursor[dst[e]], 1);
        esrc[p] = src[e];
    }
}

// ---------------- GEMM: hs[r] = bf16( relu_bn(X[r]) @ W * dinv[r] ) ----------------
// 256 threads, 64 rows/block (782 blocks -> ~3 blocks/CU), thread tile 4 rows x 8 cols.
// xl row-major with stride 33: x-reads are 4-distinct-bank 16-lane-broadcast (conflict-free).

__global__ __launch_bounds__(256) void k_gemm(
    const float* __restrict__ X, const float* __restrict__ W,
    const float* __restrict__ scale, const float* __restrict__ bn,
    unsigned short* __restrict__ hs, int n) {
    __shared__ float xl[64 * 33];    // [r][k], stride 33
    __shared__ float Wl[32 * 128];   // [k][c]
    int t = threadIdx.x;
    int row0 = blockIdx.x * 64;
    int cg = t & 15, rg = t >> 4;    // cg 0..15, rg 0..15
    int c0 = cg * 8, r0 = rg * 4;
    float acc[4][8];
    #pragma unroll
    for (int i = 0; i < 4; i++)
        #pragma unroll
        for (int j = 0; j < 8; j++) acc[i][j] = 0.f;

    for (int kk = 0; kk < 4; kk++) {
        // stage W chunk: 32x128 = 1024 float4, 4 per thread (b128, conflict-free)
        const float4* Wg4 = (const float4*)(W + kk * 32 * 128);
        float4* Wl4 = (float4*)Wl;
        #pragma unroll
        for (int j = 0; j < 4; j++) Wl4[t + j * 256] = Wg4[t + j * 256];
        // stage X chunk: 64 rows x 32 k = 512 float4, 2 per thread; scalar LDS stores
        #pragma unroll
        for (int j = 0; j < 2; j++) {
            int idx = t + j * 256;
            int r = idx >> 3, k4 = idx & 7;   // 8 lanes cover one row's 128B
            int row = row0 + r;
            float4 v = make_float4(0.f, 0.f, 0.f, 0.f);
            if (row < n) {
                v = *(const float4*)&X[(size_t)row * D + kk * 32 + k4 * 4];
                if (bn) {
                    int c = kk * 32 + k4 * 4;
                    v.x = fmaxf(v.x * bn[c + 0] + bn[128 + c + 0], 0.f);
                    v.y = fmaxf(v.y * bn[c + 1] + bn[128 + c + 1], 0.f);
                    v.z = fmaxf(v.z * bn[c + 2] + bn[128 + c + 2], 0.f);
                    v.w = fmaxf(v.w * bn[c + 3] + bn[128 + c + 3], 0.f);
                }
            }
            float* xp = &xl[r * 33 + k4 * 4];
            xp[0] = v.x; xp[1] = v.y; xp[2] = v.z; xp[3] = v.w;
        }
        __syncthreads();
        for (int k = 0; k < 32; k++) {
            float4 w0 = *(const float4*)&Wl[k * 128 + c0];
            float4 w1 = *(const float4*)&Wl[k * 128 + c0 + 4];
            float x0 = xl[(r0 + 0) * 33 + k];
            float x1 = xl[(r0 + 1) * 33 + k];
            float x2 = xl[(r0 + 2) * 33 + k];
            float x3 = xl[(r0 + 3) * 33 + k];
            float xr[4] = {x0, x1, x2, x3};
            float wc[8] = {w0.x, w0.y, w0.z, w0.w, w1.x, w1.y, w1.z, w1.w};
            #pragma unroll
            for (int i = 0; i < 4; i++)
                #pragma unroll
                for (int j = 0; j < 8; j++) acc[i][j] += xr[i] * wc[j];
        }
        __syncthreads();
    }
    // epilogue: *dinv, pack bf16, one dwordx4 store per row
    #pragma unroll
    for (int i = 0; i < 4; i++) {
        int row = row0 + r0 + i;
        if (row < n) {
            float s = scale[row];
            unsigned u[4];
            #pragma unroll
            for (int jj = 0; jj < 4; jj++) {
                __hip_bfloat16 lo = __float2bfloat16(acc[i][2 * jj] * s);
                __hip_bfloat16 hi = __float2bfloat16(acc[i][2 * jj + 1] * s);
                u[jj] = (unsigned)*(unsigned short*)&lo |
                        ((unsigned)*(unsigned short*)&hi << 16);
            }
            *(uint4*)&hs[(size_t)row * D + c0] = *(uint4*)u;
        }
    }
}

// ---------------- Column-blocked aggregation over bf16 hs ----------------
// gridDim.y = 4 passes, each pass covers 32 cols (16 dwords) => per-XCD gather
// working set 3.2MB, L2-resident. One 16-lane group per node, 16 nodes/block.

__device__ inline float2 bf2f(unsigned u) {
    union { unsigned i; float f; } lo, hi;
    lo.i = u << 16;
    hi.i = u & 0xffff0000u;
    float2 r; r.x = lo.f; r.y = hi.f; return r;
}

__global__ __launch_bounds__(256) void k_agg(
    const unsigned* __restrict__ hs, const int* __restrict__ row_ptr,
    const int* __restrict__ esrc, const float* __restrict__ dinv,
    const float* __restrict__ bias, float* __restrict__ out, int n) {
    int grp = threadIdx.x >> 4;
    int node = blockIdx.x * 16 + grp;
    if (node >= n) return;
    int sub = threadIdx.x & 15;
    int p = blockIdx.y;
    int col32 = p * 16 + sub;            // dword index within 64-dword row
    int beg = row_ptr[node], end = row_ptr[node + 1];
    float2 acc = bf2f(hs[(size_t)node * 64 + col32]);   // self loop
    for (int base = beg; base < end; base += 16) {
        int m = end - base;
        if (m > 16) m = 16;
        int eid = (base + sub < end) ? esrc[base + sub] : 0;
        int i = 0;
        for (; i + 4 <= m; i += 4) {
            int u0 = __shfl(eid, i + 0, 16);
            int u1 = __shfl(eid, i + 1, 16);
            int u2 = __shfl(eid, i + 2, 16);
            int u3 = __shfl(eid, i + 3, 16);
            unsigned p0 = hs[(size_t)u0 * 64 + col32];
            unsigned p1 = hs[(size_t)u1 * 64 + col32];
            unsigned p2 = hs[(size_t)u2 * 64 + col32];
            unsigned p3 = hs[(size_t)u3 * 64 + col32];
            float2 v0 = bf2f(p0), v1 = bf2f(p1), v2 = bf2f(p2), v3 = bf2f(p3);
            acc.x += (v0.x + v1.x) + (v2.x + v3.x);
            acc.y += (v0.y + v1.y) + (v2.y + v3.y);
        }
        for (; i < m; i++) {
            int u = __shfl(eid, i, 16);
            float2 v = bf2f(hs[(size_t)u * 64 + col32]);
            acc.x += v.x;
            acc.y += v.y;
        }
    }
    float s = dinv[node];
    float2 b = *(const float2*)&bias[col32 * 2];
    float2 r;
    r.x = acc.x * s + b.x;
    r.y = acc.y * s + b.y;
    *(float2*)&out[(size_t)node * D + col32 * 2] = r;
}

// ---------------- BatchNorm stats ----------------

__global__ __launch_bounds__(256) void k_bn_stats(const float* __restrict__ y,
                                                  float* __restrict__ stats, int n) {
    int c = threadIdx.x & 127;
    int half = threadIdx.x >> 7;
    float s = 0.f, q = 0.f;
    for (int r = blockIdx.x * 2 + half; r < n; r += gridDim.x * 2) {
        float v = y[(size_t)r * D + c];
        s += v;
        q += v * v;
    }
    __shared__ float ls[256], lq[256];
    ls[threadIdx.x] = s;
    lq[threadIdx.x] = q;
    __syncthreads();
    if (half == 0) {
        s = ls[threadIdx.x] + ls[threadIdx.x + 128];
        q = lq[threadIdx.x] + lq[threadIdx.x + 128];
        atomicAdd(&stats[c], s);
        atomicAdd(&stats[128 + c], q);
    }
}

__global__ void k_bn_finalize(float* __restrict__ stats, const float* __restrict__ gamma,
                              const float* __restrict__ beta, float n) {
    int c = threadIdx.x;  // 128 threads
    float mean = stats[c] / n;
    float var = stats[128 + c] / n - mean * mean;
    float a = gamma[c] * rsqrtf(var + 1e-5f);
    float b = beta[c] - mean * a;
    stats[c] = a;
    stats[128 + c] = b;
}

// ---------------- row L2 normalize ----------------

__global__ __launch_bounds__(256) void k_l2norm(const float* __restrict__ h,
                                                float* __restrict__ out, int n) {
    int node = blockIdx.x * 4 + (threadIdx.x >> 6);
    if (node >= n) return;
    int lane = threadIdx.x & 63;
    float2 v = *(const float2*)&h[(size_t)node * D + lane * 2];
    float pw = v.x * v.x + v.y * v.y;
    #pragma unroll
    for (int off = 32; off > 0; off >>= 1) pw += __shfl_xor(pw, off, 64);
    float sc = 1.0f / fmaxf(sqrtf(pw), 1e-12f);
    float2 r;
    r.x = v.x * sc;
    r.y = v.y * sc;
    *(float2*)&out[(size_t)node * D + lane * 2] = r;
}

// ---------------- launch ----------------

extern "C" void kernel_launch(void* const* d_in, const int* in_sizes, int n_in,
                              void* d_out, int out_size, void* d_ws, size_t ws_size,
                              hipStream_t stream) {
    const float* x  = (const float*)d_in[0];
    const int*   ei = (const int*)d_in[1];
    const float* W1 = (const float*)d_in[2];
    const float* b1 = (const float*)d_in[3];
    const float* W2 = (const float*)d_in[4];
    const float* b2 = (const float*)d_in[5];
    const float* W3 = (const float*)d_in[6];
    const float* b3 = (const float*)d_in[7];
    const float* g1 = (const float*)d_in[8];
    const float* be1 = (const float*)d_in[9];
    const float* g2 = (const float*)d_in[10];
    const float* be2 = (const float*)d_in[11];

    const int N = in_sizes[0] / D;
    const int E = in_sizes[1] / 2;
    const int* src = ei;
    const int* dst = ei + E;

    // workspace carve
    float* Y       = (float*)d_ws;              // N*D fp32
    unsigned short* hs = (unsigned short*)(Y + (size_t)N * D);  // N*D bf16
    float* dinv    = (float*)(hs + (size_t)N * D);  // N
    float* stats   = dinv + N;                  // 256
    int*   cnt     = (int*)(stats + 256);       // N
    int*   row_ptr = cnt + N;                   // N+1
    int*   cursor  = row_ptr + N + 1;           // N
    int*   bsum    = cursor + N;                // NB
    int*   boff    = bsum + 256;                // NB
    int*   esrc    = boff + 256;                // E

    const int TB = 256;
    const int gE = (E + TB - 1) / TB;
    const int NB = (N + 255) / 256;
    const int gGemm = (N + 63) / 64;
    dim3 gAgg((N + 15) / 16, 4);
    const int gNode = (N + 3) / 4;

    // CSR build
    hipMemsetAsync(cnt, 0, (size_t)N * sizeof(int), stream);
    k_count<<<gE, TB, 0, stream>>>(dst, E, cnt);
    k_scan1<<<NB, TB, 0, stream>>>(cnt, N, bsum);
    k_scan2<<<1, 256, 0, stream>>>(bsum, NB, boff);
    k_scan3<<<NB, TB, 0, stream>>>(cnt, boff, N, E, row_ptr, cursor, dinv);
    k_fill<<<gE, TB, 0, stream>>>(src, dst, E, cursor, esrc);

    // layer 1
    k_gemm<<<gGemm, TB, 0, stream>>>(x, W1, dinv, nullptr, hs, N);
    k_agg<<<gAgg, TB, 0, stream>>>((const unsigned*)hs, row_ptr, esrc, dinv, b1, Y, N);
    hipMemsetAsync(stats, 0, 256 * sizeof(float), stream);
    k_bn_stats<<<256, TB, 0, stream>>>(Y, stats, N);
    k_bn_finalize<<<1, 128, 0, stream>>>(stats, g1, be1, (float)N);

    // layer 2 (BN+ReLU fused into gemm load)
    k_gemm<<<gGemm, TB, 0, stream>>>(Y, W2, dinv, stats, hs, N);
    k_agg<<<gAgg, TB, 0, stream>>>((const unsigned*)hs, row_ptr, esrc, dinv, b2, Y, N);
    hipMemsetAsync(stats, 0, 256 * sizeof(float), stream);
    k_bn_stats<<<256, TB, 0, stream>>>(Y, stats, N);
    k_bn_finalize<<<1, 128, 0, stream>>>(stats, g2, be2, (float)N);

    // layer 3 + normalize
    k_gemm<<<gGemm, TB, 0, stream>>>(Y, W3, dinv, stats, hs, N);
    k_agg<<<gAgg, TB, 0, stream>>>((const unsigned*)hs, row_ptr, esrc, dinv, b3, Y, N);
    k_l2norm<<<gNode, TB, 0, stream>>>(Y, (float*)d_out, N);
}

// Round 5
// 490.055 us; speedup vs baseline: 1.0209x; 1.0209x over previous
//
#include <hip/hip_runtime.h>
#include <hip/hip_bf16.h>

#define D 128

// ---------------- CSR build ----------------

__global__ void k_count(const int* __restrict__ dst, int E, int* __restrict__ cnt) {
    int e = blockIdx.x * blockDim.x + threadIdx.x;
    if (e < E) atomicAdd(&cnt[dst[e]], 1);
}

// per-block sums of cnt
__global__ __launch_bounds__(256) void k_scan1(const int* __restrict__ cnt, int n,
                                               int* __restrict__ bsum) {
    int i = blockIdx.x * 256 + threadIdx.x;
    int x = (i < n) ? cnt[i] : 0;
    #pragma unroll
    for (int off = 32; off > 0; off >>= 1) x += __shfl_xor(x, off, 64);
    __shared__ int ws[4];
    if ((threadIdx.x & 63) == 0) ws[threadIdx.x >> 6] = x;
    __syncthreads();
    if (threadIdx.x == 0) bsum[blockIdx.x] = ws[0] + ws[1] + ws[2] + ws[3];
}

// exclusive scan of block sums (nb <= 256), single block of 256
__global__ void k_scan2(const int* __restrict__ bsum, int nb, int* __restrict__ boff) {
    int t = threadIdx.x;
    int lane = t & 63, wid = t >> 6;
    int x = (t < nb) ? bsum[t] : 0;
    int incl = x;
    #pragma unroll
    for (int off = 1; off < 64; off <<= 1) {
        int y = __shfl_up(incl, off, 64);
        if (lane >= off) incl += y;
    }
    __shared__ int ws[4];
    if (lane == 63) ws[wid] = incl;
    __syncthreads();
    int o = 0;
    for (int w = 0; w < wid; w++) o += ws[w];
    if (t < nb) boff[t] = o + incl - x;
}

// final: row_ptr/cursor/dinv
__global__ __launch_bounds__(256) void k_scan3(const int* __restrict__ cnt,
                                               const int* __restrict__ boff, int n, int E,
                                               int* __restrict__ row_ptr, int* __restrict__ cursor,
                                               float* __restrict__ dinv) {
    int t = threadIdx.x;
    int lane = t & 63, wid = t >> 6;
    int i = blockIdx.x * 256 + t;
    int x = (i < n) ? cnt[i] : 0;
    int incl = x;
    #pragma unroll
    for (int off = 1; off < 64; off <<= 1) {
        int y = __shfl_up(incl, off, 64);
        if (lane >= off) incl += y;
    }
    __shared__ int ws[4];
    if (lane == 63) ws[wid] = incl;
    __syncthreads();
    int o = boff[blockIdx.x];
    for (int w = 0; w < wid; w++) o += ws[w];
    if (i < n) {
        int excl = o + incl - x;
        row_ptr[i] = excl;
        cursor[i] = excl;
        dinv[i] = rsqrtf((float)(x + 1));  // +1 self loop
    }
    if (blockIdx.x == 0 && t == 0) row_ptr[n] = E;
}

__global__ void k_fill(const int* __restrict__ src, const int* __restrict__ dst, int E,
                       int* __restrict__ cursor, int* __restrict__ esrc) {
    int e = blockIdx.x * blockDim.x + threadIdx.x;
    if (e < E) {
        int p = atomicAdd(&cursor[dst[e]], 1);
        esrc[p] = src[e];
    }
}

// ---------------- GEMM: hs[r] = bf16( relu_bn(X[r]) @ W * dinv[r] ) ----------------
// 256 threads, 64 rows/block, thread tile 4 rows x 8 cols.
// Prologue: BN finalize from raw stats (stats_in: 4-way split sums), zero next stats buf.

__global__ __launch_bounds__(256) void k_gemm(
    const float* __restrict__ X, const float* __restrict__ W,
    const float* __restrict__ scale,
    const float* __restrict__ stats_in, const float* __restrict__ gamma,
    const float* __restrict__ beta, float* __restrict__ stats_zero,
    unsigned short* __restrict__ hs, int n, float invN) {
    __shared__ float xl[64 * 33];    // [r][k], stride 33
    __shared__ float Wl[32 * 128];   // [k][c]
    __shared__ float bnl[256];       // a[128], b[128]
    int t = threadIdx.x;
    if (stats_in && t < 128) {
        float s = stats_in[t] + stats_in[256 + t] + stats_in[512 + t] + stats_in[768 + t];
        float q = stats_in[128 + t] + stats_in[384 + t] + stats_in[640 + t] + stats_in[896 + t];
        float mean = s * invN;
        float var = q * invN - mean * mean;
        float a = gamma[t] * rsqrtf(var + 1e-5f);
        bnl[t] = a;
        bnl[128 + t] = beta[t] - mean * a;
    }
    if (stats_zero && blockIdx.x == 0) {
        stats_zero[t] = 0.f;
        stats_zero[t + 256] = 0.f;
        stats_zero[t + 512] = 0.f;
        stats_zero[t + 768] = 0.f;
    }
    __syncthreads();

    int row0 = blockIdx.x * 64;
    int cg = t & 15, rg = t >> 4;
    int c0 = cg * 8, r0 = rg * 4;
    float acc[4][8];
    #pragma unroll
    for (int i = 0; i < 4; i++)
        #pragma unroll
        for (int j = 0; j < 8; j++) acc[i][j] = 0.f;

    for (int kk = 0; kk < 4; kk++) {
        const float4* Wg4 = (const float4*)(W + kk * 32 * 128);
        float4* Wl4 = (float4*)Wl;
        #pragma unroll
        for (int j = 0; j < 4; j++) Wl4[t + j * 256] = Wg4[t + j * 256];
        #pragma unroll
        for (int j = 0; j < 2; j++) {
            int idx = t + j * 256;
            int r = idx >> 3, k4 = idx & 7;
            int row = row0 + r;
            float4 v = make_float4(0.f, 0.f, 0.f, 0.f);
            if (row < n) {
                v = *(const float4*)&X[(size_t)row * D + kk * 32 + k4 * 4];
                if (stats_in) {
                    int c = kk * 32 + k4 * 4;
                    v.x = fmaxf(v.x * bnl[c + 0] + bnl[128 + c + 0], 0.f);
                    v.y = fmaxf(v.y * bnl[c + 1] + bnl[128 + c + 1], 0.f);
                    v.z = fmaxf(v.z * bnl[c + 2] + bnl[128 + c + 2], 0.f);
                    v.w = fmaxf(v.w * bnl[c + 3] + bnl[128 + c + 3], 0.f);
                }
            }
            float* xp = &xl[r * 33 + k4 * 4];
            xp[0] = v.x; xp[1] = v.y; xp[2] = v.z; xp[3] = v.w;
        }
        __syncthreads();
        for (int k = 0; k < 32; k++) {
            float4 w0 = *(const float4*)&Wl[k * 128 + c0];
            float4 w1 = *(const float4*)&Wl[k * 128 + c0 + 4];
            float xr[4] = {xl[(r0 + 0) * 33 + k], xl[(r0 + 1) * 33 + k],
                           xl[(r0 + 2) * 33 + k], xl[(r0 + 3) * 33 + k]};
            float wc[8] = {w0.x, w0.y, w0.z, w0.w, w1.x, w1.y, w1.z, w1.w};
            #pragma unroll
            for (int i = 0; i < 4; i++)
                #pragma unroll
                for (int j = 0; j < 8; j++) acc[i][j] += xr[i] * wc[j];
        }
        __syncthreads();
    }
    #pragma unroll
    for (int i = 0; i < 4; i++) {
        int row = row0 + r0 + i;
        if (row < n) {
            float s = scale[row];
            unsigned u[4];
            #pragma unroll
            for (int jj = 0; jj < 4; jj++) {
                __hip_bfloat16 lo = __float2bfloat16(acc[i][2 * jj] * s);
                __hip_bfloat16 hi = __float2bfloat16(acc[i][2 * jj + 1] * s);
                u[jj] = (unsigned)*(unsigned short*)&lo |
                        ((unsigned)*(unsigned short*)&hi << 16);
            }
            *(uint4*)&hs[(size_t)row * D + c0] = *(uint4*)u;
        }
    }
}

// ---------------- Single-pass aggregation over bf16 hs, uint4 gathers ----------------
// One 16-lane group per node (16 nodes/block); lane reads uint4 = 16B => 256B row/inst.
// mode 0: accumulate BN stats (block LDS reduce -> 4-way split global atomics).
// mode 1: fused row L2-normalize (final layer).

__device__ inline float2 bf2f(unsigned u) {
    union { unsigned i; float f; } lo, hi;
    lo.i = u << 16;
    hi.i = u & 0xffff0000u;
    float2 r; r.x = lo.f; r.y = hi.f; return r;
}

__device__ inline void addu4(float* acc, uint4 p) {
    float2 a0 = bf2f(p.x), a1 = bf2f(p.y), a2 = bf2f(p.z), a3 = bf2f(p.w);
    acc[0] += a0.x; acc[1] += a0.y; acc[2] += a1.x; acc[3] += a1.y;
    acc[4] += a2.x; acc[5] += a2.y; acc[6] += a3.x; acc[7] += a3.y;
}

__global__ __launch_bounds__(256) void k_agg(
    const uint4* __restrict__ hs, const int* __restrict__ row_ptr,
    const int* __restrict__ esrc, const float* __restrict__ dinv,
    const float* __restrict__ bias, float* __restrict__ out,
    float* __restrict__ stats4, int n, int mode) {
    __shared__ float bstat[256];
    int t = threadIdx.x;
    if (mode == 0) bstat[t] = 0.f;
    int grp = t >> 4, sub = t & 15;
    int node = blockIdx.x * 16 + grp;
    bool valid = node < n;
    int nd = valid ? node : (n - 1);
    if (mode == 0) __syncthreads();

    int beg = row_ptr[nd], end = row_ptr[nd + 1];
    float acc[8];
    {
        uint4 h = hs[(size_t)nd * 16 + sub];   // self loop
        float2 a0 = bf2f(h.x), a1 = bf2f(h.y), a2 = bf2f(h.z), a3 = bf2f(h.w);
        acc[0] = a0.x; acc[1] = a0.y; acc[2] = a1.x; acc[3] = a1.y;
        acc[4] = a2.x; acc[5] = a2.y; acc[6] = a3.x; acc[7] = a3.y;
    }
    for (int base = beg; base < end; base += 16) {
        int m = end - base;
        if (m > 16) m = 16;
        int eid = (base + sub < end) ? esrc[base + sub] : 0;
        int i = 0;
        for (; i + 4 <= m; i += 4) {
            int u0 = __shfl(eid, i + 0, 16);
            int u1 = __shfl(eid, i + 1, 16);
            int u2 = __shfl(eid, i + 2, 16);
            int u3 = __shfl(eid, i + 3, 16);
            uint4 p0 = hs[(size_t)u0 * 16 + sub];
            uint4 p1 = hs[(size_t)u1 * 16 + sub];
            uint4 p2 = hs[(size_t)u2 * 16 + sub];
            uint4 p3 = hs[(size_t)u3 * 16 + sub];
            addu4(acc, p0);
            addu4(acc, p1);
            addu4(acc, p2);
            addu4(acc, p3);
        }
        for (; i < m; i++) {
            int u = __shfl(eid, i, 16);
            uint4 p = hs[(size_t)u * 16 + sub];
            addu4(acc, p);
        }
    }
    float s = dinv[nd];
    float4 b0 = *(const float4*)&bias[sub * 8];
    float4 b1 = *(const float4*)&bias[sub * 8 + 4];
    float r[8];
    r[0] = acc[0] * s + b0.x; r[1] = acc[1] * s + b0.y;
    r[2] = acc[2] * s + b0.z; r[3] = acc[3] * s + b0.w;
    r[4] = acc[4] * s + b1.x; r[5] = acc[5] * s + b1.y;
    r[6] = acc[6] * s + b1.z; r[7] = acc[7] * s + b1.w;

    if (mode == 1) {
        float p = 0.f;
        #pragma unroll
        for (int j = 0; j < 8; j++) p += r[j] * r[j];
        #pragma unroll
        for (int off = 1; off < 16; off <<= 1) p += __shfl_xor(p, off, 16);
        float sc = 1.0f / fmaxf(sqrtf(p), 1e-12f);
        #pragma unroll
        for (int j = 0; j < 8; j++) r[j] *= sc;
    }
    if (valid) {
        *(float4*)&out[(size_t)node * D + sub * 8] = make_float4(r[0], r[1], r[2], r[3]);
        *(float4*)&out[(size_t)node * D + sub * 8 + 4] = make_float4(r[4], r[5], r[6], r[7]);
    }
    if (mode == 0) {
        if (valid) {
            #pragma unroll
            for (int j = 0; j < 8; j++) {
                atomicAdd(&bstat[sub * 8 + j], r[j]);
                atomicAdd(&bstat[128 + sub * 8 + j], r[j] * r[j]);
            }
        }
        __syncthreads();
        atomicAdd(&stats4[(blockIdx.x & 3) * 256 + t], bstat[t]);
    }
}

// ---------------- launch ----------------

extern "C" void kernel_launch(void* const* d_in, const int* in_sizes, int n_in,
                              void* d_out, int out_size, void* d_ws, size_t ws_size,
                              hipStream_t stream) {
    const float* x  = (const float*)d_in[0];
    const int*   ei = (const int*)d_in[1];
    const float* W1 = (const float*)d_in[2];
    const float* b1 = (const float*)d_in[3];
    const float* W2 = (const float*)d_in[4];
    const float* b2 = (const float*)d_in[5];
    const float* W3 = (const float*)d_in[6];
    const float* b3 = (const float*)d_in[7];
    const float* g1 = (const float*)d_in[8];
    const float* be1 = (const float*)d_in[9];
    const float* g2 = (const float*)d_in[10];
    const float* be2 = (const float*)d_in[11];

    const int N = in_sizes[0] / D;
    const int E = in_sizes[1] / 2;
    const int* src = ei;
    const int* dst = ei + E;
    const float invN = 1.0f / (float)N;

    // workspace carve (16B alignment preserved for Y/hs)
    float* Y       = (float*)d_ws;                              // N*D fp32
    unsigned short* hs = (unsigned short*)(Y + (size_t)N * D);  // N*D bf16
    float* dinv    = (float*)(hs + (size_t)N * D);              // N
    float* statsA  = dinv + N;                                  // 1024
    float* statsB  = statsA + 1024;                             // 1024
    int*   cnt     = (int*)(statsB + 1024);                     // N
    int*   row_ptr = cnt + N;                                   // N+1
    int*   cursor  = row_ptr + N + 1;                           // N
    int*   bsum    = cursor + N;                                // 256
    int*   boff    = bsum + 256;                                // 256
    int*   esrc    = boff + 256;                                // E

    const int TB = 256;
    const int gE = (E + TB - 1) / TB;
    const int NB = (N + 255) / 256;
    const int gGemm = (N + 63) / 64;
    const int gAgg = (N + 15) / 16;
    const uint4* hs4 = (const uint4*)hs;

    // CSR build
    hipMemsetAsync(cnt, 0, (size_t)N * sizeof(int), stream);
    k_count<<<gE, TB, 0, stream>>>(dst, E, cnt);
    k_scan1<<<NB, TB, 0, stream>>>(cnt, N, bsum);
    k_scan2<<<1, 256, 0, stream>>>(bsum, NB, boff);
    k_scan3<<<NB, TB, 0, stream>>>(cnt, boff, N, E, row_ptr, cursor, dinv);
    k_fill<<<gE, TB, 0, stream>>>(src, dst, E, cursor, esrc);

    // layer 1 (gemm zeroes statsA; agg accumulates statsA)
    k_gemm<<<gGemm, TB, 0, stream>>>(x, W1, dinv, nullptr, nullptr, nullptr, statsA,
                                     hs, N, invN);
    k_agg<<<gAgg, TB, 0, stream>>>(hs4, row_ptr, esrc, dinv, b1, Y, statsA, N, 0);

    // layer 2 (gemm finalizes BN1 from statsA, zeroes statsB; agg accumulates statsB)
    k_gemm<<<gGemm, TB, 0, stream>>>(Y, W2, dinv, statsA, g1, be1, statsB,
                                     hs, N, invN);
    k_agg<<<gAgg, TB, 0, stream>>>(hs4, row_ptr, esrc, dinv, b2, Y, statsB, N, 0);

    // layer 3 (gemm finalizes BN2 from statsB; agg fuses L2-normalize -> d_out)
    k_gemm<<<gGemm, TB, 0, stream>>>(Y, W3, dinv, statsB, g2, be2, nullptr,
                                     hs, N, invN);
    k_agg<<<gAgg, TB, 0, stream>>>(hs4, row_ptr, esrc, dinv, b3, (float*)d_out,
                                   nullptr, N, 1);
}

// Round 7
// 443.068 us; speedup vs baseline: 1.1292x; 1.1061x over previous
//
#include <hip/hip_runtime.h>
#include <hip/hip_bf16.h>

#define D 128

typedef __bf16 bf16x8 __attribute__((ext_vector_type(8)));
typedef float floatx4 __attribute__((ext_vector_type(4)));

// ---------------- CSR build ----------------

__global__ void k_count(const int* __restrict__ dst, int E, int* __restrict__ cnt) {
    int e = blockIdx.x * blockDim.x + threadIdx.x;
    if (e < E) atomicAdd(&cnt[dst[e]], 1);
}

__global__ __launch_bounds__(256) void k_scan1(const int* __restrict__ cnt, int n,
                                               int* __restrict__ bsum) {
    int i = blockIdx.x * 256 + threadIdx.x;
    int x = (i < n) ? cnt[i] : 0;
    #pragma unroll
    for (int off = 32; off > 0; off >>= 1) x += __shfl_xor(x, off, 64);
    __shared__ int ws[4];
    if ((threadIdx.x & 63) == 0) ws[threadIdx.x >> 6] = x;
    __syncthreads();
    if (threadIdx.x == 0) bsum[blockIdx.x] = ws[0] + ws[1] + ws[2] + ws[3];
}

__global__ void k_scan2(const int* __restrict__ bsum, int nb, int* __restrict__ boff) {
    int t = threadIdx.x;
    int lane = t & 63, wid = t >> 6;
    int x = (t < nb) ? bsum[t] : 0;
    int incl = x;
    #pragma unroll
    for (int off = 1; off < 64; off <<= 1) {
        int y = __shfl_up(incl, off, 64);
        if (lane >= off) incl += y;
    }
    __shared__ int ws[4];
    if (lane == 63) ws[wid] = incl;
    __syncthreads();
    int o = 0;
    for (int w = 0; w < wid; w++) o += ws[w];
    if (t < nb) boff[t] = o + incl - x;
}

__global__ __launch_bounds__(256) void k_scan3(const int* __restrict__ cnt,
                                               const int* __restrict__ boff, int n, int E,
                                               int* __restrict__ row_ptr, int* __restrict__ cursor,
                                               float* __restrict__ dinv) {
    int t = threadIdx.x;
    int lane = t & 63, wid = t >> 6;
    int i = blockIdx.x * 256 + t;
    int x = (i < n) ? cnt[i] : 0;
    int incl = x;
    #pragma unroll
    for (int off = 1; off < 64; off <<= 1) {
        int y = __shfl_up(incl, off, 64);
        if (lane >= off) incl += y;
    }
    __shared__ int ws[4];
    if (lane == 63) ws[wid] = incl;
    __syncthreads();
    int o = boff[blockIdx.x];
    for (int w = 0; w < wid; w++) o += ws[w];
    if (i < n) {
        int excl = o + incl - x;
        row_ptr[i] = excl;
        cursor[i] = excl;
        dinv[i] = rsqrtf((float)(x + 1));  // +1 self loop
    }
    if (blockIdx.x == 0 && t == 0) row_ptr[n] = E;
}

__global__ void k_fill(const int* __restrict__ src, const int* __restrict__ dst, int E,
                       int* __restrict__ cursor, int* __restrict__ esrc) {
    int e = blockIdx.x * blockDim.x + threadIdx.x;
    if (e < E) {
        int p = atomicAdd(&cursor[dst[e]], 1);
        esrc[p] = src[e];
    }
}

// ---------------- W transpose+bf16 precompute: Wt[n][k] = bf16(W[k][n]) ----------------

__global__ __launch_bounds__(256) void k_prepw(const float* __restrict__ W1,
                                               const float* __restrict__ W2,
                                               const float* __restrict__ W3,
                                               unsigned short* __restrict__ Wt) {
    const float* W = (blockIdx.x == 0) ? W1 : (blockIdx.x == 1) ? W2 : W3;
    unsigned short* o = Wt + blockIdx.x * 16384;
    for (int i = threadIdx.x; i < 16384; i += 256) {
        int k = i >> 7, nn = i & 127;
        __hip_bfloat16 h = __float2bfloat16(W[i]);
        o[nn * 128 + k] = *(unsigned short*)&h;
    }
}

// ---------------- MFMA GEMM: hs[m][:] = bf16( relu_bn(X[m]) @ W * dinv[m] ) ----------
// D' = Wt(N x K) * X^T(K x M) = (XW)^T computed per 16x16x32 tiles.
// Wave handles 16 X-rows x 128 out-cols. Block = 4 waves = 64 rows. Grid 782.
// A-frag (Wt) from LDS (XOR chunk swizzle, b128 reads at uniform-bank floor).
// B-frag (X row) straight from global, BN+ReLU fused, cvt to bf16.
// C/D: lane holds out[m = m0+(lane&15)][n = nt*16 + quad*4 + r] -> packed 8B stores.

__global__ __launch_bounds__(256) void k_gemm(
    const float* __restrict__ X, const unsigned short* __restrict__ Wt,
    const float* __restrict__ scale, const float* __restrict__ bn,
    unsigned short* __restrict__ hs, int n) {
    __shared__ unsigned short Wl[128 * 128];
    __shared__ float bnl[256];
    int t = threadIdx.x;
    // stage Wt: 2048 uint4; chunk lc of row nn stored at physical chunk lc^(nn&15)
    {
        const uint4* wg = (const uint4*)Wt;
        uint4* wl4 = (uint4*)Wl;
        #pragma unroll
        for (int j = 0; j < 8; j++) {
            int idx = j * 256 + t;
            int nn = idx >> 4, lc = idx & 15;
            wl4[nn * 16 + (lc ^ (nn & 15))] = wg[idx];
        }
    }
    if (bn) bnl[t] = bn[t];
    __syncthreads();

    int l = t & 63, w = t >> 6;
    int lm = l & 15, quad = l >> 4;
    int m = blockIdx.x * 64 + w * 16 + lm;
    int rm = (m < n) ? m : (n - 1);
    const float* xrow = X + (size_t)rm * D;

    floatx4 acc[8];
    #pragma unroll
    for (int nt = 0; nt < 8; nt++) acc[nt] = (floatx4){0.f, 0.f, 0.f, 0.f};

    #pragma unroll
    for (int ks = 0; ks < 4; ks++) {
        int k0 = ks * 32 + quad * 8;
        float4 xa = *(const float4*)(xrow + k0);
        float4 xb = *(const float4*)(xrow + k0 + 4);
        if (bn) {
            float4 a0 = *(const float4*)&bnl[k0];
            float4 a1 = *(const float4*)&bnl[k0 + 4];
            float4 c0 = *(const float4*)&bnl[128 + k0];
            float4 c1 = *(const float4*)&bnl[128 + k0 + 4];
            xa.x = fmaxf(xa.x * a0.x + c0.x, 0.f);
            xa.y = fmaxf(xa.y * a0.y + c0.y, 0.f);
            xa.z = fmaxf(xa.z * a0.z + c0.z, 0.f);
            xa.w = fmaxf(xa.w * a0.w + c0.w, 0.f);
            xb.x = fmaxf(xb.x * a1.x + c1.x, 0.f);
            xb.y = fmaxf(xb.y * a1.y + c1.y, 0.f);
            xb.z = fmaxf(xb.z * a1.z + c1.z, 0.f);
            xb.w = fmaxf(xb.w * a1.w + c1.w, 0.f);
        }
        bf16x8 xf;
        xf[0] = (__bf16)xa.x; xf[1] = (__bf16)xa.y;
        xf[2] = (__bf16)xa.z; xf[3] = (__bf16)xa.w;
        xf[4] = (__bf16)xb.x; xf[5] = (__bf16)xb.y;
        xf[6] = (__bf16)xb.z; xf[7] = (__bf16)xb.w;
        int pc = (ks * 4 + quad) ^ lm;
        #pragma unroll
        for (int nt = 0; nt < 8; nt++) {
            const bf16x8 wf = *(const bf16x8*)&Wl[(nt * 16 + lm) * 128 + pc * 8];
            acc[nt] = __builtin_amdgcn_mfma_f32_16x16x32_bf16(wf, xf, acc[nt], 0, 0, 0);
        }
    }

    float s = scale[rm];
    if (m < n) {
        #pragma unroll
        for (int nt = 0; nt < 8; nt++) {
            __hip_bfloat16 h0 = __float2bfloat16(acc[nt][0] * s);
            __hip_bfloat16 h1 = __float2bfloat16(acc[nt][1] * s);
            __hip_bfloat16 h2 = __float2bfloat16(acc[nt][2] * s);
            __hip_bfloat16 h3 = __float2bfloat16(acc[nt][3] * s);
            uint2 uu;
            uu.x = (unsigned)*(unsigned short*)&h0 | ((unsigned)*(unsigned short*)&h1 << 16);
            uu.y = (unsigned)*(unsigned short*)&h2 | ((unsigned)*(unsigned short*)&h3 << 16);
            *(uint2*)&hs[(size_t)m * D + nt * 16 + quad * 4] = uu;
        }
    }
}

// ---------------- Column-blocked aggregation over bf16 hs (round-4 proven) ----------
// gridDim.y = 4 passes x 32 cols (16 dwords): per-XCD gather slice 3.2MB = L2-resident.

__device__ inline float2 bf2f(unsigned u) {
    union { unsigned i; float f; } lo, hi;
    lo.i = u << 16;
    hi.i = u & 0xffff0000u;
    float2 r; r.x = lo.f; r.y = hi.f; return r;
}

__global__ __launch_bounds__(256) void k_agg(
    const unsigned* __restrict__ hs, const int* __restrict__ row_ptr,
    const int* __restrict__ esrc, const float* __restrict__ dinv,
    const float* __restrict__ bias, float* __restrict__ out, int n) {
    int grp = threadIdx.x >> 4;
    int node = blockIdx.x * 16 + grp;
    if (node >= n) return;
    int sub = threadIdx.x & 15;
    int p = blockIdx.y;
    int col32 = p * 16 + sub;
    int beg = row_ptr[node], end = row_ptr[node + 1];
    float2 acc = bf2f(hs[(size_t)node * 64 + col32]);   // self loop
    for (int base = beg; base < end; base += 16) {
        int m = end - base;
        if (m > 16) m = 16;
        int eid = (base + sub < end) ? esrc[base + sub] : 0;
        int i = 0;
        for (; i + 8 <= m; i += 8) {
            int u0 = __shfl(eid, i + 0, 16);
            int u1 = __shfl(eid, i + 1, 16);
            int u2 = __shfl(eid, i + 2, 16);
            int u3 = __shfl(eid, i + 3, 16);
            int u4 = __shfl(eid, i + 4, 16);
            int u5 = __shfl(eid, i + 5, 16);
            int u6 = __shfl(eid, i + 6, 16);
            int u7 = __shfl(eid, i + 7, 16);
            unsigned p0 = hs[(size_t)u0 * 64 + col32];
            unsigned p1 = hs[(size_t)u1 * 64 + col32];
            unsigned p2 = hs[(size_t)u2 * 64 + col32];
            unsigned p3 = hs[(size_t)u3 * 64 + col32];
            unsigned p4 = hs[(size_t)u4 * 64 + col32];
            unsigned p5 = hs[(size_t)u5 * 64 + col32];
            unsigned p6 = hs[(size_t)u6 * 64 + col32];
            unsigned p7 = hs[(size_t)u7 * 64 + col32];
            float2 v0 = bf2f(p0), v1 = bf2f(p1), v2 = bf2f(p2), v3 = bf2f(p3);
            float2 v4 = bf2f(p4), v5 = bf2f(p5), v6 = bf2f(p6), v7 = bf2f(p7);
            acc.x += ((v0.x + v1.x) + (v2.x + v3.x)) + ((v4.x + v5.x) + (v6.x + v7.x));
            acc.y += ((v0.y + v1.y) + (v2.y + v3.y)) + ((v4.y + v5.y) + (v6.y + v7.y));
        }
        for (; i + 4 <= m; i += 4) {
            int u0 = __shfl(eid, i + 0, 16);
            int u1 = __shfl(eid, i + 1, 16);
            int u2 = __shfl(eid, i + 2, 16);
            int u3 = __shfl(eid, i + 3, 16);
            unsigned p0 = hs[(size_t)u0 * 64 + col32];
            unsigned p1 = hs[(size_t)u1 * 64 + col32];
            unsigned p2 = hs[(size_t)u2 * 64 + col32];
            unsigned p3 = hs[(size_t)u3 * 64 + col32];
            float2 v0 = bf2f(p0), v1 = bf2f(p1), v2 = bf2f(p2), v3 = bf2f(p3);
            acc.x += (v0.x + v1.x) + (v2.x + v3.x);
            acc.y += (v0.y + v1.y) + (v2.y + v3.y);
        }
        for (; i < m; i++) {
            int u = __shfl(eid, i, 16);
            float2 v = bf2f(hs[(size_t)u * 64 + col32]);
            acc.x += v.x;
            acc.y += v.y;
        }
    }
    float s = dinv[node];
    float2 b = *(const float2*)&bias[col32 * 2];
    float2 r;
    r.x = acc.x * s + b.x;
    r.y = acc.y * s + b.y;
    *(float2*)&out[(size_t)node * D + col32 * 2] = r;
}

// ---------------- BatchNorm ----------------

__global__ __launch_bounds__(256) void k_bn_stats(const float* __restrict__ y,
                                                  float* __restrict__ stats, int n) {
    int c = threadIdx.x & 127;
    int half = threadIdx.x >> 7;
    float s = 0.f, q = 0.f;
    for (int r = blockIdx.x * 2 + half; r < n; r += gridDim.x * 2) {
        float v = y[(size_t)r * D + c];
        s += v;
        q += v * v;
    }
    __shared__ float ls[256], lq[256];
    ls[threadIdx.x] = s;
    lq[threadIdx.x] = q;
    __syncthreads();
    if (half == 0) {
        s = ls[threadIdx.x] + ls[threadIdx.x + 128];
        q = lq[threadIdx.x] + lq[threadIdx.x + 128];
        atomicAdd(&stats[c], s);
        atomicAdd(&stats[128 + c], q);
    }
}

__global__ void k_bn_finalize(float* __restrict__ stats, const float* __restrict__ gamma,
                              const float* __restrict__ beta, float n) {
    int c = threadIdx.x;  // 128 threads
    float mean = stats[c] / n;
    float var = stats[128 + c] / n - mean * mean;
    float a = gamma[c] * rsqrtf(var + 1e-5f);
    float b = beta[c] - mean * a;
    stats[c] = a;
    stats[128 + c] = b;
}

// ---------------- row L2 normalize ----------------

__global__ __launch_bounds__(256) void k_l2norm(const float* __restrict__ h,
                                                float* __restrict__ out, int n) {
    int node = blockIdx.x * 4 + (threadIdx.x >> 6);
    if (node >= n) return;
    int lane = threadIdx.x & 63;
    float2 v = *(const float2*)&h[(size_t)node * D + lane * 2];
    float pw = v.x * v.x + v.y * v.y;
    #pragma unroll
    for (int off = 32; off > 0; off >>= 1) pw += __shfl_xor(pw, off, 64);
    float sc = 1.0f / fmaxf(sqrtf(pw), 1e-12f);
    float2 r;
    r.x = v.x * sc;
    r.y = v.y * sc;
    *(float2*)&out[(size_t)node * D + lane * 2] = r;
}

// ---------------- launch ----------------

extern "C" void kernel_launch(void* const* d_in, const int* in_sizes, int n_in,
                              void* d_out, int out_size, void* d_ws, size_t ws_size,
                              hipStream_t stream) {
    const float* x  = (const float*)d_in[0];
    const int*   ei = (const int*)d_in[1];
    const float* W1 = (const float*)d_in[2];
    const float* b1 = (const float*)d_in[3];
    const float* W2 = (const float*)d_in[4];
    const float* b2 = (const float*)d_in[5];
    const float* W3 = (const float*)d_in[6];
    const float* b3 = (const float*)d_in[7];
    const float* g1 = (const float*)d_in[8];
    const float* be1 = (const float*)d_in[9];
    const float* g2 = (const float*)d_in[10];
    const float* be2 = (const float*)d_in[11];

    const int N = in_sizes[0] / D;
    const int E = in_sizes[1] / 2;
    const int* src = ei;
    const int* dst = ei + E;

    // workspace carve (all segments 16B-aligned)
    float* Y       = (float*)d_ws;                              // N*D fp32
    unsigned short* hs = (unsigned short*)(Y + (size_t)N * D);  // N*D bf16
    float* dinv    = (float*)(hs + (size_t)N * D);              // N
    float* stats   = dinv + N;                                  // 256
    unsigned short* wt = (unsigned short*)(stats + 256);        // 3*16384 bf16
    int*   cnt     = (int*)(wt + 3 * 16384);                    // N
    int*   row_ptr = cnt + N;                                   // N+1
    int*   cursor  = row_ptr + N + 1;                           // N
    int*   bsum    = cursor + N;                                // 256
    int*   boff    = bsum + 256;                                // 256
    int*   esrc    = boff + 256;                                // E

    const int TB = 256;
    const int gE = (E + TB - 1) / TB;
    const int NB = (N + 255) / 256;
    const int gGemm = (N + 63) / 64;
    dim3 gAgg((N + 15) / 16, 4);
    const int gNode = (N + 3) / 4;

    // W transpose/bf16 precompute + CSR build
    k_prepw<<<3, TB, 0, stream>>>(W1, W2, W3, wt);
    hipMemsetAsync(cnt, 0, (size_t)N * sizeof(int), stream);
    k_count<<<gE, TB, 0, stream>>>(dst, E, cnt);
    k_scan1<<<NB, TB, 0, stream>>>(cnt, N, bsum);
    k_scan2<<<1, 256, 0, stream>>>(bsum, NB, boff);
    k_scan3<<<NB, TB, 0, stream>>>(cnt, boff, N, E, row_ptr, cursor, dinv);
    k_fill<<<gE, TB, 0, stream>>>(src, dst, E, cursor, esrc);

    // layer 1
    k_gemm<<<gGemm, TB, 0, stream>>>(x, wt, dinv, nullptr, hs, N);
    k_agg<<<gAgg, TB, 0, stream>>>((const unsigned*)hs, row_ptr, esrc, dinv, b1, Y, N);
    hipMemsetAsync(stats, 0, 256 * sizeof(float), stream);
    k_bn_stats<<<256, TB, 0, stream>>>(Y, stats, N);
    k_bn_finalize<<<1, 128, 0, stream>>>(stats, g1, be1, (float)N);

    // layer 2 (BN+ReLU fused into gemm load)
    k_gemm<<<gGemm, TB, 0, stream>>>(Y, wt + 16384, dinv, stats, hs, N);
    k_agg<<<gAgg, TB, 0, stream>>>((const unsigned*)hs, row_ptr, esrc, dinv, b2, Y, N);
    hipMemsetAsync(stats, 0, 256 * sizeof(float), stream);
    k_bn_stats<<<256, TB, 0, stream>>>(Y, stats, N);
    k_bn_finalize<<<1, 128, 0, stream>>>(stats, g2, be2, (float)N);

    // layer 3 + normalize
    k_gemm<<<gGemm, TB, 0, stream>>>(Y, wt + 32768, dinv, stats, hs, N);
    k_agg<<<gAgg, TB, 0, stream>>>((const unsigned*)hs, row_ptr, esrc, dinv, b3, Y, N);
    k_l2norm<<<gNode, TB, 0, stream>>>(Y, (float*)d_out, N);
}

// Round 8
// 414.581 us; speedup vs baseline: 1.2068x; 1.0687x over previous
//
#include <hip/hip_runtime.h>
#include <hip/hip_bf16.h>

#define D 128

typedef __bf16 bf16x8 __attribute__((ext_vector_type(8)));
typedef float floatx4 __attribute__((ext_vector_type(4)));

// ---------------- CSR build ----------------

__global__ void k_count(const int* __restrict__ dst, int E, int* __restrict__ cnt) {
    int e = blockIdx.x * blockDim.x + threadIdx.x;
    if (e < E) atomicAdd(&cnt[dst[e]], 1);
}

__global__ __launch_bounds__(256) void k_scan1(const int* __restrict__ cnt, int n,
                                               int* __restrict__ bsum) {
    int i = blockIdx.x * 256 + threadIdx.x;
    int x = (i < n) ? cnt[i] : 0;
    #pragma unroll
    for (int off = 32; off > 0; off >>= 1) x += __shfl_xor(x, off, 64);
    __shared__ int ws[4];
    if ((threadIdx.x & 63) == 0) ws[threadIdx.x >> 6] = x;
    __syncthreads();
    if (threadIdx.x == 0) bsum[blockIdx.x] = ws[0] + ws[1] + ws[2] + ws[3];
}

__global__ void k_scan2(const int* __restrict__ bsum, int nb, int* __restrict__ boff) {
    int t = threadIdx.x;
    int lane = t & 63, wid = t >> 6;
    int x = (t < nb) ? bsum[t] : 0;
    int incl = x;
    #pragma unroll
    for (int off = 1; off < 64; off <<= 1) {
        int y = __shfl_up(incl, off, 64);
        if (lane >= off) incl += y;
    }
    __shared__ int ws[4];
    if (lane == 63) ws[wid] = incl;
    __syncthreads();
    int o = 0;
    for (int w = 0; w < wid; w++) o += ws[w];
    if (t < nb) boff[t] = o + incl - x;
}

__global__ __launch_bounds__(256) void k_scan3(const int* __restrict__ cnt,
                                               const int* __restrict__ boff, int n, int E,
                                               int* __restrict__ row_ptr, int* __restrict__ cursor,
                                               float* __restrict__ dinv) {
    int t = threadIdx.x;
    int lane = t & 63, wid = t >> 6;
    int i = blockIdx.x * 256 + t;
    int x = (i < n) ? cnt[i] : 0;
    int incl = x;
    #pragma unroll
    for (int off = 1; off < 64; off <<= 1) {
        int y = __shfl_up(incl, off, 64);
        if (lane >= off) incl += y;
    }
    __shared__ int ws[4];
    if (lane == 63) ws[wid] = incl;
    __syncthreads();
    int o = boff[blockIdx.x];
    for (int w = 0; w < wid; w++) o += ws[w];
    if (i < n) {
        int excl = o + incl - x;
        row_ptr[i] = excl;
        cursor[i] = excl;
        dinv[i] = rsqrtf((float)(x + 1));  // +1 self loop
    }
    if (blockIdx.x == 0 && t == 0) row_ptr[n] = E;
}

// Range-partitioned fill: blockIdx.y = dst-range (8 ranges). Each range-group
// scans all edges, keeps those with dst in range -> CSR writes land in a
// ~200KB L2-resident window (lines fill before eviction). u16 payload (N<65536).
__global__ __launch_bounds__(256) void k_fill(const int* __restrict__ src,
                                              const int* __restrict__ dst, int E,
                                              int* __restrict__ cursor,
                                              unsigned short* __restrict__ esrc, int n) {
    int rs = (n + 7) >> 3;
    int lo = blockIdx.y * rs, hi = lo + rs;
    int step = gridDim.x * 256;
    for (int e = blockIdx.x * 256 + threadIdx.x; e < E; e += step) {
        int d = dst[e];
        int s = src[e];
        if (d >= lo && d < hi) {
            int p = atomicAdd(&cursor[d], 1);
            esrc[p] = (unsigned short)s;
        }
    }
}

// ---------------- W transpose+bf16 precompute: Wt[n][k] = bf16(W[k][n]) ----------------

__global__ __launch_bounds__(256) void k_prepw(const float* __restrict__ W1,
                                               const float* __restrict__ W2,
                                               const float* __restrict__ W3,
                                               unsigned short* __restrict__ Wt) {
    const float* W = (blockIdx.x == 0) ? W1 : (blockIdx.x == 1) ? W2 : W3;
    unsigned short* o = Wt + blockIdx.x * 16384;
    for (int i = threadIdx.x; i < 16384; i += 256) {
        int k = i >> 7, nn = i & 127;
        __hip_bfloat16 h = __float2bfloat16(W[i]);
        o[nn * 128 + k] = *(unsigned short*)&h;
    }
}

// ---------------- MFMA GEMM: hs[m][:] = bf16( relu_bn(X[m]) @ W * dinv[m] ) ----------
// Prologue: finalize BN coefs from 4-way-split raw sums (stats_in), zero next stats buf.

__global__ __launch_bounds__(256) void k_gemm(
    const float* __restrict__ X, const unsigned short* __restrict__ Wt,
    const float* __restrict__ scale, const float* __restrict__ stats_in,
    const float* __restrict__ gamma, const float* __restrict__ beta,
    float* __restrict__ stats_zero,
    unsigned short* __restrict__ hs, int n, float invN) {
    __shared__ unsigned short Wl[128 * 128];
    __shared__ float bnl[256];
    int t = threadIdx.x;
    if (stats_in && t < 128) {
        float s = stats_in[t] + stats_in[256 + t] + stats_in[512 + t] + stats_in[768 + t];
        float q = stats_in[128 + t] + stats_in[384 + t] + stats_in[640 + t] + stats_in[896 + t];
        float mean = s * invN;
        float var = q * invN - mean * mean;
        float a = gamma[t] * rsqrtf(var + 1e-5f);
        bnl[t] = a;
        bnl[128 + t] = beta[t] - mean * a;
    }
    if (stats_zero && blockIdx.x == 0) {
        stats_zero[t] = 0.f;
        stats_zero[256 + t] = 0.f;
        stats_zero[512 + t] = 0.f;
        stats_zero[768 + t] = 0.f;
    }
    // stage Wt: 2048 uint4; chunk lc of row nn stored at physical chunk lc^(nn&15)
    {
        const uint4* wg = (const uint4*)Wt;
        uint4* wl4 = (uint4*)Wl;
        #pragma unroll
        for (int j = 0; j < 8; j++) {
            int idx = j * 256 + t;
            int nn = idx >> 4, lc = idx & 15;
            wl4[nn * 16 + (lc ^ (nn & 15))] = wg[idx];
        }
    }
    __syncthreads();

    int l = t & 63, w = t >> 6;
    int lm = l & 15, quad = l >> 4;
    int m = blockIdx.x * 64 + w * 16 + lm;
    int rm = (m < n) ? m : (n - 1);
    const float* xrow = X + (size_t)rm * D;

    floatx4 acc[8];
    #pragma unroll
    for (int nt = 0; nt < 8; nt++) acc[nt] = (floatx4){0.f, 0.f, 0.f, 0.f};

    #pragma unroll
    for (int ks = 0; ks < 4; ks++) {
        int k0 = ks * 32 + quad * 8;
        float4 xa = *(const float4*)(xrow + k0);
        float4 xb = *(const float4*)(xrow + k0 + 4);
        if (stats_in) {
            float4 a0 = *(const float4*)&bnl[k0];
            float4 a1 = *(const float4*)&bnl[k0 + 4];
            float4 c0 = *(const float4*)&bnl[128 + k0];
            float4 c1 = *(const float4*)&bnl[128 + k0 + 4];
            xa.x = fmaxf(xa.x * a0.x + c0.x, 0.f);
            xa.y = fmaxf(xa.y * a0.y + c0.y, 0.f);
            xa.z = fmaxf(xa.z * a0.z + c0.z, 0.f);
            xa.w = fmaxf(xa.w * a0.w + c0.w, 0.f);
            xb.x = fmaxf(xb.x * a1.x + c1.x, 0.f);
            xb.y = fmaxf(xb.y * a1.y + c1.y, 0.f);
            xb.z = fmaxf(xb.z * a1.z + c1.z, 0.f);
            xb.w = fmaxf(xb.w * a1.w + c1.w, 0.f);
        }
        bf16x8 xf;
        xf[0] = (__bf16)xa.x; xf[1] = (__bf16)xa.y;
        xf[2] = (__bf16)xa.z; xf[3] = (__bf16)xa.w;
        xf[4] = (__bf16)xb.x; xf[5] = (__bf16)xb.y;
        xf[6] = (__bf16)xb.z; xf[7] = (__bf16)xb.w;
        int pc = (ks * 4 + quad) ^ lm;
        #pragma unroll
        for (int nt = 0; nt < 8; nt++) {
            const bf16x8 wf = *(const bf16x8*)&Wl[(nt * 16 + lm) * 128 + pc * 8];
            acc[nt] = __builtin_amdgcn_mfma_f32_16x16x32_bf16(wf, xf, acc[nt], 0, 0, 0);
        }
    }

    float s = scale[rm];
    if (m < n) {
        #pragma unroll
        for (int nt = 0; nt < 8; nt++) {
            __hip_bfloat16 h0 = __float2bfloat16(acc[nt][0] * s);
            __hip_bfloat16 h1 = __float2bfloat16(acc[nt][1] * s);
            __hip_bfloat16 h2 = __float2bfloat16(acc[nt][2] * s);
            __hip_bfloat16 h3 = __float2bfloat16(acc[nt][3] * s);
            uint2 uu;
            uu.x = (unsigned)*(unsigned short*)&h0 | ((unsigned)*(unsigned short*)&h1 << 16);
            uu.y = (unsigned)*(unsigned short*)&h2 | ((unsigned)*(unsigned short*)&h3 << 16);
            *(uint2*)&hs[(size_t)m * D + nt * 16 + quad * 4] = uu;
        }
    }
}

// ---------------- Column-blocked aggregation (4 passes x 64B line slice) ----------
// 16-lane group handles 4 consecutive nodes; gather loop identical to round-7 proven.
// mode 0: accumulate BN stats (LDS reduce -> 4-way-split global atomics).

__device__ inline float2 bf2f(unsigned u) {
    union { unsigned i; float f; } lo, hi;
    lo.i = u << 16;
    hi.i = u & 0xffff0000u;
    float2 r; r.x = lo.f; r.y = hi.f; return r;
}

__global__ __launch_bounds__(256) void k_agg(
    const unsigned* __restrict__ hs, const int* __restrict__ row_ptr,
    const unsigned short* __restrict__ esrc, const float* __restrict__ dinv,
    const float* __restrict__ bias, float* __restrict__ out,
    float* __restrict__ stats4, int n, int mode) {
    __shared__ float ls0[256], ls1[256], lq0[256], lq1[256];
    int t = threadIdx.x;
    int grp = t >> 4, sub = t & 15;
    int p = blockIdx.y;
    int col32 = p * 16 + sub;
    float s0 = 0.f, s1 = 0.f, q0 = 0.f, q1 = 0.f;
    int node0 = blockIdx.x * 64 + grp * 4;
    float2 b = *(const float2*)&bias[col32 * 2];

    for (int ni = 0; ni < 4; ni++) {
        int node = node0 + ni;
        if (node >= n) break;
        int beg = row_ptr[node], end = row_ptr[node + 1];
        float2 acc = bf2f(hs[(size_t)node * 64 + col32]);   // self loop
        for (int base = beg; base < end; base += 16) {
            int m = end - base;
            if (m > 16) m = 16;
            int eid = (base + sub < end) ? (int)esrc[base + sub] : 0;
            int i = 0;
            for (; i + 8 <= m; i += 8) {
                int u0 = __shfl(eid, i + 0, 16);
                int u1 = __shfl(eid, i + 1, 16);
                int u2 = __shfl(eid, i + 2, 16);
                int u3 = __shfl(eid, i + 3, 16);
                int u4 = __shfl(eid, i + 4, 16);
                int u5 = __shfl(eid, i + 5, 16);
                int u6 = __shfl(eid, i + 6, 16);
                int u7 = __shfl(eid, i + 7, 16);
                unsigned p0 = hs[(size_t)u0 * 64 + col32];
                unsigned p1 = hs[(size_t)u1 * 64 + col32];
                unsigned p2 = hs[(size_t)u2 * 64 + col32];
                unsigned p3 = hs[(size_t)u3 * 64 + col32];
                unsigned p4 = hs[(size_t)u4 * 64 + col32];
                unsigned p5 = hs[(size_t)u5 * 64 + col32];
                unsigned p6 = hs[(size_t)u6 * 64 + col32];
                unsigned p7 = hs[(size_t)u7 * 64 + col32];
                float2 v0 = bf2f(p0), v1 = bf2f(p1), v2 = bf2f(p2), v3 = bf2f(p3);
                float2 v4 = bf2f(p4), v5 = bf2f(p5), v6 = bf2f(p6), v7 = bf2f(p7);
                acc.x += ((v0.x + v1.x) + (v2.x + v3.x)) + ((v4.x + v5.x) + (v6.x + v7.x));
                acc.y += ((v0.y + v1.y) + (v2.y + v3.y)) + ((v4.y + v5.y) + (v6.y + v7.y));
            }
            for (; i + 4 <= m; i += 4) {
                int u0 = __shfl(eid, i + 0, 16);
                int u1 = __shfl(eid, i + 1, 16);
                int u2 = __shfl(eid, i + 2, 16);
                int u3 = __shfl(eid, i + 3, 16);
                unsigned p0 = hs[(size_t)u0 * 64 + col32];
                unsigned p1 = hs[(size_t)u1 * 64 + col32];
                unsigned p2 = hs[(size_t)u2 * 64 + col32];
                unsigned p3 = hs[(size_t)u3 * 64 + col32];
                float2 v0 = bf2f(p0), v1 = bf2f(p1), v2 = bf2f(p2), v3 = bf2f(p3);
                acc.x += (v0.x + v1.x) + (v2.x + v3.x);
                acc.y += (v0.y + v1.y) + (v2.y + v3.y);
            }
            for (; i < m; i++) {
                int u = __shfl(eid, i, 16);
                float2 v = bf2f(hs[(size_t)u * 64 + col32]);
                acc.x += v.x;
                acc.y += v.y;
            }
        }
        float sc = dinv[node];
        float2 r;
        r.x = acc.x * sc + b.x;
        r.y = acc.y * sc + b.y;
        *(float2*)&out[(size_t)node * D + col32 * 2] = r;
        s0 += r.x; s1 += r.y;
        q0 += r.x * r.x; q1 += r.y * r.y;
    }

    if (mode == 0) {
        ls0[t] = s0; ls1[t] = s1; lq0[t] = q0; lq1[t] = q1;
        __syncthreads();
        if (t < 16) {
            float a0 = 0.f, a1 = 0.f, c0 = 0.f, c1 = 0.f;
            for (int g = 0; g < 16; g++) {
                int i = g * 16 + t;
                a0 += ls0[i]; a1 += ls1[i];
                c0 += lq0[i]; c1 += lq1[i];
            }
            float* sbuf = stats4 + (blockIdx.x & 3) * 256;
            atomicAdd(&sbuf[p * 32 + 2 * t], a0);
            atomicAdd(&sbuf[p * 32 + 2 * t + 1], a1);
            atomicAdd(&sbuf[128 + p * 32 + 2 * t], c0);
            atomicAdd(&sbuf[128 + p * 32 + 2 * t + 1], c1);
        }
    }
}

// ---------------- row L2 normalize ----------------

__global__ __launch_bounds__(256) void k_l2norm(const float* __restrict__ h,
                                                float* __restrict__ out, int n) {
    int node = blockIdx.x * 4 + (threadIdx.x >> 6);
    if (node >= n) return;
    int lane = threadIdx.x & 63;
    float2 v = *(const float2*)&h[(size_t)node * D + lane * 2];
    float pw = v.x * v.x + v.y * v.y;
    #pragma unroll
    for (int off = 32; off > 0; off >>= 1) pw += __shfl_xor(pw, off, 64);
    float sc = 1.0f / fmaxf(sqrtf(pw), 1e-12f);
    float2 r;
    r.x = v.x * sc;
    r.y = v.y * sc;
    *(float2*)&out[(size_t)node * D + lane * 2] = r;
}

// ---------------- launch ----------------

extern "C" void kernel_launch(void* const* d_in, const int* in_sizes, int n_in,
                              void* d_out, int out_size, void* d_ws, size_t ws_size,
                              hipStream_t stream) {
    const float* x  = (const float*)d_in[0];
    const int*   ei = (const int*)d_in[1];
    const float* W1 = (const float*)d_in[2];
    const float* b1 = (const float*)d_in[3];
    const float* W2 = (const float*)d_in[4];
    const float* b2 = (const float*)d_in[5];
    const float* W3 = (const float*)d_in[6];
    const float* b3 = (const float*)d_in[7];
    const float* g1 = (const float*)d_in[8];
    const float* be1 = (const float*)d_in[9];
    const float* g2 = (const float*)d_in[10];
    const float* be2 = (const float*)d_in[11];

    const int N = in_sizes[0] / D;
    const int E = in_sizes[1] / 2;
    const int* src = ei;
    const int* dst = ei + E;
    const float invN = 1.0f / (float)N;

    // workspace carve
    float* Y       = (float*)d_ws;                              // N*D fp32
    unsigned short* hs = (unsigned short*)(Y + (size_t)N * D);  // N*D bf16
    float* dinv    = (float*)(hs + (size_t)N * D);              // N
    float* statsA  = dinv + N;                                  // 1024
    float* statsB  = statsA + 1024;                             // 1024
    unsigned short* wt = (unsigned short*)(statsB + 1024);      // 3*16384 bf16
    int*   cnt     = (int*)(wt + 3 * 16384);                    // N
    int*   row_ptr = cnt + N;                                   // N+1
    int*   cursor  = row_ptr + N + 1;                           // N
    int*   bsum    = cursor + N;                                // 256
    int*   boff    = bsum + 256;                                // 256
    unsigned short* esrc = (unsigned short*)(boff + 256);       // E u16

    const int TB = 256;
    const int gE = (E + TB - 1) / TB;
    const int NB = (N + 255) / 256;
    const int gGemm = (N + 63) / 64;
    dim3 gFill(112, 8);
    dim3 gAgg((N + 63) / 64, 4);
    const int gNode = (N + 3) / 4;

    // W precompute + CSR build
    k_prepw<<<3, TB, 0, stream>>>(W1, W2, W3, wt);
    hipMemsetAsync(cnt, 0, (size_t)N * sizeof(int), stream);
    k_count<<<gE, TB, 0, stream>>>(dst, E, cnt);
    k_scan1<<<NB, TB, 0, stream>>>(cnt, N, bsum);
    k_scan2<<<1, 256, 0, stream>>>(bsum, NB, boff);
    k_scan3<<<NB, TB, 0, stream>>>(cnt, boff, N, E, row_ptr, cursor, dinv);
    k_fill<<<gFill, TB, 0, stream>>>(src, dst, E, cursor, esrc, N);

    // layer 1 (gemm1 zeroes statsA; agg1 accumulates statsA)
    k_gemm<<<gGemm, TB, 0, stream>>>(x, wt, dinv, nullptr, nullptr, nullptr, statsA,
                                     hs, N, invN);
    k_agg<<<gAgg, TB, 0, stream>>>((const unsigned*)hs, row_ptr, esrc, dinv, b1, Y,
                                   statsA, N, 0);

    // layer 2 (gemm2 finalizes BN1 from statsA, zeroes statsB)
    k_gemm<<<gGemm, TB, 0, stream>>>(Y, wt + 16384, dinv, statsA, g1, be1, statsB,
                                     hs, N, invN);
    k_agg<<<gAgg, TB, 0, stream>>>((const unsigned*)hs, row_ptr, esrc, dinv, b2, Y,
                                   statsB, N, 0);

    // layer 3 (gemm3 finalizes BN2 from statsB) + normalize
    k_gemm<<<gGemm, TB, 0, stream>>>(Y, wt + 32768, dinv, statsB, g2, be2, nullptr,
                                     hs, N, invN);
    k_agg<<<gAgg, TB, 0, stream>>>((const unsigned*)hs, row_ptr, esrc, dinv, b3, Y,
                                   nullptr, N, 1);
    k_l2norm<<<gNode, TB, 0, stream>>>(Y, (float*)d_out, N);
}